// Round 11
// baseline (218.475 us; speedup 1.0000x reference)
//
#include <hip/hip_runtime.h>

#define N_NODES 50000
#define N_EDGES 800000
#define F_IN   128
#define F_MID  64
#define F_OUT  40

// ---- counting-sort CSR build ----
#define SLICE_SHIFT 8
#define SLICE_SZ    256                  // nodes per slice (pow2)
#define NSLICE      196                  // ceil(50000/256)
#define PCHUNKS     256                  // edge chunks for bucket passes
#define PCHUNK_E    ((N_EDGES + PCHUNKS - 1) / PCHUNKS)   // 3125
#define NCOUNT      (NSLICE * PCHUNKS)   // 50176

// edge pack: src (16 bits, 50000 < 65536) | dst-within-slice (8 bits) << 16

// ---------------- phase A: per-(chunk,slice) counts, LDS histogram ----------------

__global__ __launch_bounds__(256) void bucket_count(const int* __restrict__ ei,
                                                    int* __restrict__ counts) {
    __shared__ int cnt[NSLICE];
    if (threadIdx.x < NSLICE) cnt[threadIdx.x] = 0;
    __syncthreads();
    int e0 = blockIdx.x * PCHUNK_E;
    int e1 = e0 + PCHUNK_E; if (e1 > N_EDGES) e1 = N_EDGES;
    for (int e = e0 + threadIdx.x; e < e1; e += 256) {
        int c = ei[N_EDGES + e];
        atomicAdd(&cnt[c >> SLICE_SHIFT], 1);
    }
    __syncthreads();
    // slice-major layout: counts[s * PCHUNKS + chunk]
    if (threadIdx.x < NSLICE) counts[threadIdx.x * PCHUNKS + blockIdx.x] = cnt[threadIdx.x];
}

// ---------------- phase B: hierarchical exclusive scan of counts -> choff ----------------

__global__ __launch_bounds__(256) void sc_bsum(const int* __restrict__ counts, int* __restrict__ bsum) {
    int idx = blockIdx.x * 256 + threadIdx.x;
    int v = (idx < NCOUNT) ? counts[idx] : 0;
#pragma unroll
    for (int off = 32; off > 0; off >>= 1) v += __shfl_xor(v, off, 64);
    __shared__ int ws[4];
    if ((threadIdx.x & 63) == 0) ws[threadIdx.x >> 6] = v;
    __syncthreads();
    if (threadIdx.x == 0) bsum[blockIdx.x] = ws[0] + ws[1] + ws[2] + ws[3];
}

__global__ __launch_bounds__(256) void sc_bscan(const int* __restrict__ bsum, int* __restrict__ boff) {
    int tid = threadIdx.x;
    int lane = tid & 63, wv = tid >> 6;
    int v = (tid < NSLICE) ? bsum[tid] : 0;
    int inc = v;
#pragma unroll
    for (int s = 1; s < 64; s <<= 1) {
        int t = __shfl_up(inc, s, 64);
        if (lane >= s) inc += t;
    }
    __shared__ int ws[4];
    if (lane == 63) ws[wv] = inc;
    __syncthreads();
    int woff = 0;
    for (int w = 0; w < wv; ++w) woff += ws[w];
    if (tid < NSLICE) boff[tid] = woff + inc - v;   // exclusive prefix of block sums
}

__global__ __launch_bounds__(256) void sc_bscan2(const int* __restrict__ counts,
                                                 const int* __restrict__ boff,
                                                 int* __restrict__ choff) {
    int idx = blockIdx.x * 256 + threadIdx.x;
    int lane = threadIdx.x & 63, wv = threadIdx.x >> 6;
    int v = (idx < NCOUNT) ? counts[idx] : 0;
    int inc = v;
#pragma unroll
    for (int s = 1; s < 64; s <<= 1) {
        int t = __shfl_up(inc, s, 64);
        if (lane >= s) inc += t;
    }
    __shared__ int ws[4];
    if (lane == 63) ws[wv] = inc;
    __syncthreads();
    int off = boff[blockIdx.x];
    for (int w = 0; w < wv; ++w) off += ws[w];
    if (idx < NCOUNT) choff[idx] = off + inc - v;
}

// ---------------- phase C: scatter packed edges into per-(slice,chunk) ranges ----------------

__global__ __launch_bounds__(256) void bucket_scatter(const int* __restrict__ ei,
                                                      const int* __restrict__ choff,
                                                      int* __restrict__ pairs) {
    __shared__ int cur[NSLICE];
    if (threadIdx.x < NSLICE) cur[threadIdx.x] = choff[threadIdx.x * PCHUNKS + blockIdx.x];
    __syncthreads();
    int e0 = blockIdx.x * PCHUNK_E;
    int e1 = e0 + PCHUNK_E; if (e1 > N_EDGES) e1 = N_EDGES;
    for (int e = e0 + threadIdx.x; e < e1; e += 256) {
        int r = ei[e];
        int c = ei[N_EDGES + e];
        int pos = atomicAdd(&cur[c >> SLICE_SHIFT], 1);
        pairs[pos] = r | ((c & (SLICE_SZ - 1)) << 16);
    }
}

// ---------------- phase D: per-slice CSR build (rowptr, dinv, srcs) ----------------

__global__ __launch_bounds__(256) void slice_csr(const int* __restrict__ pairs,
                                                 const int* __restrict__ choff,
                                                 int* __restrict__ rowptr,
                                                 float* __restrict__ dinv,
                                                 int* __restrict__ srcs) {
    __shared__ int hist[SLICE_SZ];
    __shared__ int wpart[4];
    int s = blockIdx.x;
    int base = choff[s * PCHUNKS];
    int end  = (s == NSLICE - 1) ? N_EDGES : choff[(s + 1) * PCHUNKS];
    int tid = threadIdx.x;
    hist[tid] = 0;
    __syncthreads();
    for (int i = base + tid; i < end; i += 256)
        atomicAdd(&hist[pairs[i] >> 16], 1);
    __syncthreads();
    int v = hist[tid];
    int lane = tid & 63, wv = tid >> 6;
    int inc = v;
#pragma unroll
    for (int st = 1; st < 64; st <<= 1) {
        int t = __shfl_up(inc, st, 64);
        if (lane >= st) inc += t;
    }
    if (lane == 63) wpart[wv] = inc;
    __syncthreads();
    int woff = 0;
    for (int w = 0; w < wv; ++w) woff += wpart[w];
    int ex = woff + inc - v;                 // exclusive prefix within slice
    __syncthreads();
    hist[tid] = ex;                          // reuse hist as cursor (own slot only)
    int node = s * SLICE_SZ + tid;
    if (node < N_NODES) {
        rowptr[node] = base + ex;
        dinv[node]   = rsqrtf((float)v + 1.0f);   // +1 = self loop
    }
    if (node == N_NODES - 1) rowptr[N_NODES] = N_EDGES;
    __syncthreads();
    for (int i = base + tid; i < end; i += 256) {
        int p = pairs[i];
        int pos = atomicAdd(&hist[p >> 16], 1);
        srcs[base + pos] = p & 0xFFFF;
    }
}

// ---------------- GEMM1: hw1s = (x @ W1) * dinv[row]  (128 -> 64, pre-scaled) ----------------

__global__ __launch_bounds__(256) void gemm1_kernel(const float* __restrict__ x,
                                                    const float* __restrict__ W1,
                                                    const float* __restrict__ dinv,
                                                    float* __restrict__ hw1s) {
    __shared__ float sW[F_IN * F_MID];   // 32 KB, row-major [k][c]
    __shared__ float sX[64][68];         // 17 KB, one K-half, padded
    int tid = threadIdx.x;
    const float4* W4 = (const float4*)W1;
    float4* sW4 = (float4*)sW;
    for (int i = tid; i < F_IN * F_MID / 4; i += 256) sW4[i] = W4[i];

    int row0 = blockIdx.x * 64;
    int tx = tid & 15, ty = tid >> 4;
    int c0 = tx * 4, r0 = ty * 4;
    float acc[4][4] = {};

    for (int p = 0; p < 2; ++p) {
        __syncthreads();
#pragma unroll
        for (int it = 0; it < 4; ++it) {
            int i = (tid + it * 256) * 4;      // element index in 64x64 tile
            int r = i >> 6, k = i & 63;
            float4 v = make_float4(0.f, 0.f, 0.f, 0.f);
            if (row0 + r < N_NODES)
                v = *(const float4*)&x[(size_t)(row0 + r) * F_IN + p * 64 + k];
            *(float4*)&sX[r][k] = v;
        }
        __syncthreads();
        const float* sWp = sW + p * 64 * F_MID;
#pragma unroll 4
        for (int k = 0; k < 64; ++k) {
            float4 w = *(const float4*)&sWp[k * F_MID + c0];
            float a0 = sX[r0 + 0][k];
            float a1 = sX[r0 + 1][k];
            float a2 = sX[r0 + 2][k];
            float a3 = sX[r0 + 3][k];
            acc[0][0] = fmaf(a0, w.x, acc[0][0]); acc[0][1] = fmaf(a0, w.y, acc[0][1]);
            acc[0][2] = fmaf(a0, w.z, acc[0][2]); acc[0][3] = fmaf(a0, w.w, acc[0][3]);
            acc[1][0] = fmaf(a1, w.x, acc[1][0]); acc[1][1] = fmaf(a1, w.y, acc[1][1]);
            acc[1][2] = fmaf(a1, w.z, acc[1][2]); acc[1][3] = fmaf(a1, w.w, acc[1][3]);
            acc[2][0] = fmaf(a2, w.x, acc[2][0]); acc[2][1] = fmaf(a2, w.y, acc[2][1]);
            acc[2][2] = fmaf(a2, w.z, acc[2][2]); acc[2][3] = fmaf(a2, w.w, acc[2][3]);
            acc[3][0] = fmaf(a3, w.x, acc[3][0]); acc[3][1] = fmaf(a3, w.y, acc[3][1]);
            acc[3][2] = fmaf(a3, w.z, acc[3][2]); acc[3][3] = fmaf(a3, w.w, acc[3][3]);
        }
    }
#pragma unroll
    for (int j = 0; j < 4; ++j) {
        int row = row0 + r0 + j;
        if (row < N_NODES) {
            float d = dinv[row];
            float4 o = make_float4(acc[j][0] * d, acc[j][1] * d, acc[j][2] * d, acc[j][3] * d);
            *(float4*)&hw1s[(size_t)row * F_MID + c0] = o;
        }
    }
}

// ---------------- gather1: 4 edges/instr via float4 lanes ----------------
// lane = (edge-in-quad egrp = lane>>4, feature-quad fid = lane&15).
// Per iteration: 1 bpermute shuffle + 1 dwordx4 load = 1 KB/wave-instr.
// Epilogue: shfl_xor(16,32) folds edge groups; lanes 0..15 write float4.

__global__ __launch_bounds__(256) void gather1_kernel(const int* __restrict__ rowptr,
                                                      const int* __restrict__ srcs,
                                                      const float* __restrict__ hw1s,
                                                      const float* __restrict__ dinv,
                                                      const float* __restrict__ b1,
                                                      float* __restrict__ h) {
    int n = blockIdx.x * 4 + (threadIdx.x >> 6);
    int lane = threadIdx.x & 63;
    if (n >= N_NODES) return;
    int s = rowptr[n], e = rowptr[n + 1];
    int egrp = lane >> 4;          // 0..3: which edge of the quad
    int fid  = lane & 15;          // feature quad: floats 4*fid .. 4*fid+3
    float4 acc = make_float4(0.f, 0.f, 0.f, 0.f);
    for (int base = s; base < e; base += 64) {
        int cnt = e - base; if (cnt > 64) cnt = 64;
        int ms = (lane < cnt) ? srcs[base + lane] : 0;
        for (int j = 0; j < cnt; j += 4) {
            int src = __shfl(ms, j + egrp, 64);      // j+egrp <= 63 (j<=60)
            if (j + egrp < cnt) {
                float4 v = *(const float4*)&hw1s[(size_t)src * F_MID + 4 * fid];
                acc.x += v.x; acc.y += v.y; acc.z += v.z; acc.w += v.w;
            }
        }
    }
    // fold the 4 edge groups (stride 16)
    acc.x += __shfl_xor(acc.x, 16, 64); acc.y += __shfl_xor(acc.y, 16, 64);
    acc.z += __shfl_xor(acc.z, 16, 64); acc.w += __shfl_xor(acc.w, 16, 64);
    acc.x += __shfl_xor(acc.x, 32, 64); acc.y += __shfl_xor(acc.y, 32, 64);
    acc.z += __shfl_xor(acc.z, 32, 64); acc.w += __shfl_xor(acc.w, 32, 64);
    if (lane < 16) {
        float d = dinv[n];
        float4 sv = *(const float4*)&hw1s[(size_t)n * F_MID + 4 * lane];
        float4 bb = *(const float4*)&b1[4 * lane];
        float4 hv;
        hv.x = fmaxf(fmaf(d, acc.x + sv.x, bb.x), 0.f);
        hv.y = fmaxf(fmaf(d, acc.y + sv.y, bb.y), 0.f);
        hv.z = fmaxf(fmaf(d, acc.z + sv.z, bb.z), 0.f);
        hv.w = fmaxf(fmaf(d, acc.w + sv.w, bb.w), 0.f);
        *(float4*)&h[(size_t)n * F_MID + 4 * lane] = hv;
    }
}

// ---------------- GEMM2: hw2s = (h @ W2) * dinv[row]  (64 -> 40, pre-scaled) ----------------

__global__ __launch_bounds__(256) void gemm2_kernel(const float* __restrict__ h,
                                                    const float* __restrict__ W2,
                                                    const float* __restrict__ dinv,
                                                    float* __restrict__ hw2s) {
    __shared__ float sW[F_MID * F_OUT];  // 10 KB
    for (int i = threadIdx.x; i < F_MID * F_OUT; i += 256) sW[i] = W2[i];
    __syncthreads();
    int idx = blockIdx.x * 256 + threadIdx.x;
    if (idx >= N_NODES * F_OUT) return;
    int r = idx / F_OUT;
    int c = idx % F_OUT;
    float acc = 0.f;
#pragma unroll
    for (int k = 0; k < F_MID; ++k) acc = fmaf(h[(size_t)r * F_MID + k], sW[k * F_OUT + c], acc);
    hw2s[idx] = acc * dinv[r];
}

// ---------------- gather2 + softmax: 3 edges/instr via float2 over 20 lanes ----------------
// lane = (edge-in-triple egrp = lane/20, feature-pair fid = lane%20); lanes 60..63 idle.
// Group fold via 3 direct shuffles; softmax reductions use full-wave identities.

__global__ __launch_bounds__(256) void gather2_softmax_kernel(const int* __restrict__ rowptr,
                                                              const int* __restrict__ srcs,
                                                              const float* __restrict__ hw2s,
                                                              const float* __restrict__ dinv,
                                                              const float* __restrict__ b2,
                                                              float* __restrict__ out) {
    int n = blockIdx.x * 4 + (threadIdx.x >> 6);
    int lane = threadIdx.x & 63;
    if (n >= N_NODES) return;
    int s = rowptr[n], e = rowptr[n + 1];
    int egrp = lane / 20;            // 0,1,2 (3 for idle lanes 60..63)
    int fid  = lane - egrp * 20;     // 0..19 -> floats 2*fid, 2*fid+1
    bool act = egrp < 3;
    float2 acc = make_float2(0.f, 0.f);
    for (int base = s; base < e; base += 64) {
        int cnt = e - base; if (cnt > 64) cnt = 64;
        int ms = (lane < cnt) ? srcs[base + lane] : 0;
        for (int j = 0; j < cnt; j += 3) {
            int sl = j + egrp; int slc = sl > 63 ? 63 : sl;
            int src = __shfl(ms, slc, 64);
            if (act && sl < cnt) {
                float2 v = *(const float2*)&hw2s[(size_t)src * F_OUT + 2 * fid];
                acc.x += v.x; acc.y += v.y;
            }
        }
    }
    // fold the 3 edge groups: lanes <20 pull from lanes fid, fid+20, fid+40
    float sx = __shfl(acc.x, fid, 64) + __shfl(acc.x, fid + 20, 64) + __shfl(acc.x, fid + 40, 64);
    float sy = __shfl(acc.y, fid, 64) + __shfl(acc.y, fid + 20, 64) + __shfl(acc.y, fid + 40, 64);
    float d = dinv[n];
    float lx = -3.402823466e38f, ly = -3.402823466e38f;
    if (lane < 20) {
        float2 sv = *(const float2*)&hw2s[(size_t)n * F_OUT + 2 * lane];
        float2 bb = *(const float2*)&b2[2 * lane];
        lx = fmaf(d, sx + sv.x, bb.x);
        ly = fmaf(d, sy + sv.y, bb.y);
    }
    float m = fmaxf(lx, ly);
#pragma unroll
    for (int off = 32; off > 0; off >>= 1) m = fmaxf(m, __shfl_xor(m, off, 64));
    float px = (lane < 20) ? __expf(lx - m) : 0.f;
    float py = (lane < 20) ? __expf(ly - m) : 0.f;
    float su = px + py;
#pragma unroll
    for (int off = 32; off > 0; off >>= 1) su += __shfl_xor(su, off, 64);
    if (lane < 20) {
        float2 o = make_float2(px / su, py / su);
        *(float2*)&out[(size_t)n * F_OUT + 2 * lane] = o;
    }
}

// ---------------- launch ----------------

extern "C" void kernel_launch(void* const* d_in, const int* in_sizes, int n_in,
                              void* d_out, int out_size, void* d_ws, size_t ws_size,
                              hipStream_t stream) {
    const float* x  = (const float*)d_in[0];
    const int*   ei = (const int*)d_in[1];
    const float* W1 = (const float*)d_in[2];
    const float* b1 = (const float*)d_in[3];
    const float* W2 = (const float*)d_in[4];
    const float* b2 = (const float*)d_in[5];
    float* out = (float*)d_out;

    char* ws = (char*)d_ws;
    size_t off = 0;
    auto alloc = [&](size_t bytes) -> void* {
        void* p = ws + off;
        off += (bytes + 255) & ~(size_t)255;
        return p;
    };
    int*   counts = (int*)  alloc(NCOUNT * sizeof(int));
    int*   bsum   = (int*)  alloc(NSLICE * sizeof(int));
    int*   boff   = (int*)  alloc(NSLICE * sizeof(int));
    int*   choff  = (int*)  alloc(NCOUNT * sizeof(int));
    int*   pairs  = (int*)  alloc((size_t)N_EDGES * sizeof(int));
    int*   rowptr = (int*)  alloc((N_NODES + 1) * sizeof(int));
    float* dinv   = (float*)alloc(N_NODES * sizeof(float));
    int*   srcs   = (int*)  alloc((size_t)N_EDGES * sizeof(int));
    float* hw1s   = (float*)alloc((size_t)N_NODES * F_MID * sizeof(float));
    float* h      = (float*)alloc((size_t)N_NODES * F_MID * sizeof(float));
    float* hw2s   = (float*)alloc((size_t)N_NODES * F_OUT * sizeof(float));

    bucket_count  <<<PCHUNKS, 256, 0, stream>>>(ei, counts);
    sc_bsum       <<<(NCOUNT + 255) / 256, 256, 0, stream>>>(counts, bsum);
    sc_bscan      <<<1, 256, 0, stream>>>(bsum, boff);
    sc_bscan2     <<<(NCOUNT + 255) / 256, 256, 0, stream>>>(counts, boff, choff);
    bucket_scatter<<<PCHUNKS, 256, 0, stream>>>(ei, choff, pairs);
    slice_csr     <<<NSLICE, 256, 0, stream>>>(pairs, choff, rowptr, dinv, srcs);
    gemm1_kernel  <<<(N_NODES + 63) / 64, 256, 0, stream>>>(x, W1, dinv, hw1s);
    gather1_kernel<<<(N_NODES + 3) / 4, 256, 0, stream>>>(rowptr, srcs, hw1s, dinv, b1, h);
    gemm2_kernel  <<<(N_NODES * F_OUT + 255) / 256, 256, 0, stream>>>(h, W2, dinv, hw2s);
    gather2_softmax_kernel<<<(N_NODES + 3) / 4, 256, 0, stream>>>(rowptr, srcs, hw2s, dinv, b2, out);
}